// Round 6
// baseline (755.069 us; speedup 1.0000x reference)
//
#include <hip/hip_runtime.h>
#include <cstdint>
#include <cstddef>

// ---------------------------------------------------------------------------
// NN_each_LN_exp: 33x33 SAME convs on 32x32 maps = dense 1024x1024 linear
// operators -> f16 MFMA GEMMs. Row layout r = n*4+k: the 16x16x32 MFMA acc
// quad holds all 4 colors of one (n,o) cell -> epilogue fusion lane-local.
// R6: phase A = 3 pure-async GEMM jobs (precomputed one-hot f16 A arrays,
// no VALU expansion); stage1 K=1024 + deferred mk_sa pass; BN=256 blocks
// (wave tile 64x128) to cut LDS reads/FLOP by 33% and amortize the s-tile.
// ---------------------------------------------------------------------------

typedef _Float16 f16;
typedef __attribute__((ext_vector_type(8))) _Float16 f16x8;
typedef __attribute__((ext_vector_type(4))) float f32x4;

#define NB   4096
#define PIX  1024
#define MR   (NB * 4)

__device__ __forceinline__ void gld_lds16(const void* g, void* l) {
    __builtin_amdgcn_global_load_lds(
        (const __attribute__((address_space(1))) void*)g,
        (__attribute__((address_space(3))) void*)l, 16, 0, 0);
}

// Conv matrices: Mn, Mn2 (1024x1024), BstS1 = Me+Mn (1024x1024),
// BstE (2048x1024: rows [0,1024)=Mem, rows [1024,2048)=Mem+Mn)
__global__ void build_mats(const float* __restrict__ we, const float* __restrict__ wn,
                           const float* __restrict__ wn2, const float* __restrict__ wem,
                           f16* __restrict__ Mn, f16* __restrict__ Mn2,
                           f16* __restrict__ BstS1, f16* __restrict__ BstE) {
    int idx = blockIdx.x * 256 + threadIdx.x;      // over 1024*1024
    int o = idx >> 10, in = idx & 1023;
    int i = o >> 5, j = o & 31, a = in >> 5, b = in & 31;
    int u = a - i + 16, v = b - j + 16;
    bool ok = (u >= 0) && (u < 33) && (v >= 0) && (v < 33);
    int w = u * 33 + v;
    float ve = 0.f, vn = 0.f, vn2 = 0.f, vem = 0.f;
    if (ok) { ve = we[w]; vn = wn[w]; vn2 = wn2[w]; vem = wem[w]; }
    Mn[idx]    = (f16)vn;
    Mn2[idx]   = (f16)vn2;
    BstS1[idx] = (f16)(ve + vn);
    BstE[idx]                          = (f16)vem;
    BstE[(size_t)(1024 + o) * 1024 + in] = (f16)(vem + vn);
}

// t_n[o] = sum_j Mn[o][j]
__global__ void tn_build(const f16* __restrict__ Mn, float* __restrict__ tn) {
    int o = blockIdx.x * 256 + threadIdx.x;
    float s = 0.f;
    for (int j = 0; j < 128; j++) {
        f16x8 v = *(const f16x8*)(Mn + (size_t)o * 1024 + j * 8);
#pragma unroll
        for (int e = 0; e < 8; e++) s += (float)v[e];
    }
    tn[o] = s;
}

// W1 (100,1024) fp32 -> padded (128,1024) f16
__global__ void build_w1(const float* __restrict__ W1, f16* __restrict__ W1b) {
    int idx = blockIdx.x * 256 + threadIdx.x;
    int j = idx >> 10, i = idx & 1023;
    W1b[idx] = (f16)(j < 100 ? W1[j * 1024 + i] : 0.f);
}

// dots (34,32,4096) int32, (v,h,b) -> board[n*1024+p] bytes, LDS transpose
__global__ void build_board(const int* __restrict__ dots, unsigned char* __restrict__ board) {
    __shared__ unsigned char tile[64][68];
    int t = threadIdx.x;
    int bp = blockIdx.x & 15, bn = blockIdx.x >> 4;
    int p0 = bp * 64, n0 = bn * 64;
    int ln = t & 63, lp = t >> 6;
#pragma unroll
    for (int j = 0; j < 16; j++) {
        int p = lp * 16 + j;
        tile[p][ln] = (unsigned char)dots[(size_t)(p0 + p) * 4096 + n0 + ln];
    }
    __syncthreads();
#pragma unroll
    for (int j = 0; j < 16; j++) {
        int n = lp * 16 + j;
        board[(size_t)(n0 + n) * 1024 + p0 + ln] = tile[ln][n];
    }
}

// board -> one-hot f16 operand arrays
__global__ void build_masks(const unsigned char* __restrict__ board,
                            f16* __restrict__ Xe, f16* __restrict__ Xn,
                            f16* __restrict__ Xz) {
    int idx = blockIdx.x * 256 + threadIdx.x;      // n*1024+p
    int n = idx >> 10, p = idx & 1023;
    int c = board[idx];
    Xz[idx] = (f16)(c == 0 ? 1.f : 0.f);
    size_t base = (size_t)n * 4096 + p;
#pragma unroll
    for (int k = 0; k < 4; k++) {
        Xe[base + k * 1024] = (f16)((c == k + 1) ? 1.f : 0.f);
        Xn[base + k * 1024] = (f16)((c != 0 && c != k + 1) ? 1.f : 0.f);
    }
}

// Lsel / Sa from raw stage1 outputs
__global__ void mk_sa(const f16* __restrict__ S1sel, const f16* __restrict__ EplusM,
                      const unsigned char* __restrict__ board,
                      float* __restrict__ Lsel, f16* __restrict__ Sa) {
    int idx = blockIdx.x * 256 + threadIdx.x;      // n*1024+o
    int c = board[idx];
    float L = (c > 0) ? ((float)S1sel[idx] + (float)EplusM[idx]) : 0.f;
    Lsel[idx] = L;
    Sa[idx] = (f16)(1.f / (1.f + __expf(-L)));
}

// ---------------------------------------------------------------------------
// Core GEMM: C(M x N) = A(M x 1024) * B(N x 1024)^T, f16 in, f32 acc.
// BM=128, BN=NTJ*32, BK=64, 4 waves as 2x2; wave tile 64 x NTJ*16.
// 16x16x32 MFMA, XOR-swizzled chunks (R2-verified conflict-free frag reads).
// ASRC: 0 direct f16   1 NC*s (frag-time v_pk mul)
// MODE: 0 f16-out ldo  1 S1sel select  2 E-dual (En | Eplus-tn)
//       3 depth        4 depth-final   5 f32 leaky (MLP1)
// ---------------------------------------------------------------------------
template <int MODE, int ASRC, int NTJ>
__device__ __forceinline__ void run_gemm(
    int bjob, int ypx, int nx, char* smem,
    const f16* __restrict__ X, const f16* __restrict__ B,
    const unsigned char* __restrict__ board, const f16* __restrict__ NCs,
    const f16* __restrict__ Sin, const f16* __restrict__ En,
    const float* __restrict__ tn, float* __restrict__ Lsel,
    f16* __restrict__ outB, int ldo, float* __restrict__ outF) {
    constexpr int BN = NTJ * 32;
    char* smB = smem;                              // BN*128 bytes
    char* smA = smem + BN * 128;                   // 16 KB (A or NC)
    char* smS = smA + 16384;                       // 4 KB s tile (ASRC1)

    const int tid = threadIdx.x;
    const int wv = tid >> 6, ln = tid & 63;
    const int wm = wv >> 1, wn_ = wv & 1;
    const int lr = ln & 15, lq = ln >> 4;

    int xcd = bjob & 7, slot = bjob >> 3;
    int bx = slot % nx;
    int by = xcd * ypx + slot / nx;
    const int rtile = by * 128, otile = bx * BN;
    const int img0 = rtile >> 2;                   // ASRC1 s-map base

    const f32x4 fz = {0.f, 0.f, 0.f, 0.f};
    f32x4 acc[4][NTJ];
#pragma unroll
    for (int i = 0; i < 4; i++)
#pragma unroll
        for (int j = 0; j < NTJ; j++) acc[i][j] = fz;

    for (int kb = 0; kb < 1024; kb += 64) {
        // ---- async staging, XOR-swizzled 16B chunks ----
#pragma unroll
        for (int t = 0; t < NTJ; t++) {            // B: BN*8 chunk slots
            int c = t * 256 + wv * 64 + ln;
            int row = c >> 3, gcol = (c & 7) ^ (row & 7);
            gld_lds16(B + (size_t)(otile + row) * 1024 + kb + gcol * 8, smB + c * 16);
        }
#pragma unroll
        for (int t = 0; t < 4; t++) {              // A / NC: 1024 slots
            int c = t * 256 + wv * 64 + ln;
            int row = c >> 3, gcol = (c & 7) ^ (row & 7);
            const f16* src = (ASRC == 0) ? X : NCs;
            gld_lds16(src + (size_t)(rtile + row) * 1024 + kb + gcol * 8, smA + c * 16);
        }
        if (ASRC == 1) {                           // s: 256 slots
            int c = wv * 64 + ln;
            int row = c >> 3, gcol = (c & 7) ^ (row & 7);
            gld_lds16(Sin + (size_t)(img0 + row) * 1024 + kb + gcol * 8, smS + c * 16);
        }
        __syncthreads();

        // ---- compute ----
#pragma unroll
        for (int kk = 0; kk < 2; kk++) {
            const int oct = kk * 4 + lq;
            f16x8 af[4];
#pragma unroll
            for (int i = 0; i < 4; i++) {
                int rrow = wm * 64 + i * 16 + lr;
                if (ASRC == 0) {
                    af[i] = *(const f16x8*)(smA + rrow * 128 + (oct ^ (rrow & 7)) * 16);
                } else {
                    f16x8 nc = *(const f16x8*)(smA + rrow * 128 + (oct ^ (rrow & 7)) * 16);
                    int img = rrow >> 2;
                    f16x8 sv = *(const f16x8*)(smS + img * 128 + (oct ^ (img & 7)) * 16);
                    af[i] = nc * sv;
                }
            }
#pragma unroll
            for (int j = 0; j < NTJ; j++) {
                int brow = wn_ * (NTJ * 16) + j * 16 + lr;
                f16x8 bf = *(const f16x8*)(smB + brow * 128 + (oct ^ (brow & 7)) * 16);
#pragma unroll
                for (int i = 0; i < 4; i++)
                    acc[i][j] = __builtin_amdgcn_mfma_f32_16x16x32_f16(
                        af[i], bf, acc[i][j], 0, 0, 0);
            }
        }
        __syncthreads();
    }

    // ---- epilogue ----
#pragma unroll
    for (int i = 0; i < 4; i++) {
        int rbase = rtile + wm * 64 + i * 16 + lq * 4;
#pragma unroll
        for (int j = 0; j < NTJ; j++) {
            int o = otile + wn_ * (NTJ * 16) + j * 16 + lr;
            f32x4 a = acc[i][j];
            if (MODE == 0) {
#pragma unroll
                for (int v = 0; v < 4; v++)
                    outB[(size_t)(rbase + v) * ldo + o] = (f16)a[v];
            } else if (MODE == 2) {                // rows are n; dual region
#pragma unroll
                for (int v = 0; v < 4; v++) {
                    int n = rbase + v;
                    if (o < 1024)
                        outB[(size_t)n * 1024 + o] = (f16)a[v];               // En
                    else
                        outB[(size_t)(NB + n) * 1024 + (o - 1024)] =
                            (f16)(a[v] - tn[o - 1024]);                        // Eplus-tn
                }
            } else if (MODE == 5) {
#pragma unroll
                for (int v = 0; v < 4; v++) {
                    float x = a[v];
                    outF[(size_t)(rbase + v) * ldo + o] = x > 0.f ? x : 0.2f * x;
                }
            } else {                               // 1,3,4: quad = 4 colors of cell n
                int n = rbase >> 2;
                size_t no = (size_t)n * PIX + o;
                int c = board[no];
                float asel = (c == 1) ? a[0] : (c == 2) ? a[1] : (c == 3) ? a[2] : a[3];
                if (MODE == 1) {
                    outB[no] = (f16)asel;          // raw conv_{we+wn}(each_c)
                } else {
                    float E = (float)En[no];
                    float Lnew = (c > 0) ? (Lsel[no] + E + asel) : 0.f;
                    float s = 1.f / (1.f + __expf(-Lnew));
                    if (MODE != 4) Lsel[no] = Lnew;
                    outB[no] = (f16)s;
                }
            }
        }
    }
}

// Phase A: [0,512) stage1-raw, [512,1024) NC, [1024,1280) E-dual
__global__ void __launch_bounds__(256, 3) gemm_fa(
    const f16* __restrict__ Xe, const f16* __restrict__ Xn,
    const f16* __restrict__ Xz, const f16* __restrict__ BstS1,
    const f16* __restrict__ Mn, const f16* __restrict__ BstE,
    const unsigned char* __restrict__ board, const float* __restrict__ tn,
    f16* __restrict__ S1sel, f16* __restrict__ NC, f16* __restrict__ EnBoth) {
    __shared__ __attribute__((aligned(16))) char smem[49152];
    int bi = blockIdx.x;
    if (bi < 512) {
        run_gemm<1, 0, 8>(bi, 16, 4, smem, Xe, BstS1, board, nullptr, nullptr,
                          nullptr, nullptr, nullptr, S1sel, 0, nullptr);
    } else if (bi < 1024) {
        run_gemm<0, 0, 8>(bi - 512, 16, 4, smem, Xn, Mn, nullptr, nullptr, nullptr,
                          nullptr, nullptr, nullptr, NC, PIX, nullptr);
    } else {
        run_gemm<2, 0, 8>(bi - 1024, 4, 8, smem, Xz, BstE, nullptr, nullptr, nullptr,
                          nullptr, tn, nullptr, EnBoth, 0, nullptr);
    }
}

// Depth GEMM (A = NC*s), MODE 3 (update L, write s) or 4 (write feat)
template <int MODE>
__global__ void __launch_bounds__(256, 3) gemm_depth(
    const f16* __restrict__ Mn2, const unsigned char* __restrict__ board,
    const f16* __restrict__ NCs, const f16* __restrict__ Sin,
    const f16* __restrict__ En, float* __restrict__ Lsel,
    f16* __restrict__ outB) {
    __shared__ __attribute__((aligned(16))) char smem[53248];
    run_gemm<MODE, 1, 8>(blockIdx.x, 16, 4, smem, nullptr, Mn2, board, NCs,
                         Sin, En, nullptr, Lsel, outB, 0, nullptr);
}

// MLP layer 1: X1 = leaky(feat @ W1b^T), N=128
__global__ void __launch_bounds__(256, 3) gemm_mlp(
    const f16* __restrict__ feat, const f16* __restrict__ W1b,
    float* __restrict__ X1) {
    __shared__ __attribute__((aligned(16))) char smem[32768];
    run_gemm<5, 0, 4>(blockIdx.x, 4, 1, smem, feat, W1b, nullptr, nullptr,
                      nullptr, nullptr, nullptr, nullptr, nullptr, 128, X1);
}

// MLP layers 2+3
__global__ void __launch_bounds__(256) mlp23(const float* __restrict__ X1,
                                             const float* __restrict__ W2,
                                             const float* __restrict__ W3,
                                             float* __restrict__ out) {
    __shared__ float sW2[10000];
    __shared__ float sW3[100];
    __shared__ float red[256];
    int t = threadIdx.x;
    for (int idx = t; idx < 10000; idx += 256) sW2[idx] = W2[idx];
    if (t < 100) sW3[t] = W3[t];
    __syncthreads();
    int nb = t >> 2, q = t & 3;
    int n = blockIdx.x * 64 + nb;
    const float* x1 = X1 + (size_t)n * 128;
    float xr[100];
#pragma unroll
    for (int i = 0; i < 100; i++) xr[i] = x1[i];
    float partial = 0.f;
    for (int jj = 0; jj < 25; jj++) {
        int j = q + jj * 4;
        const float* w2r = sW2 + j * 100;
        float acc2 = 0.f;
#pragma unroll
        for (int i = 0; i < 100; i++) acc2 += w2r[i] * xr[i];
        partial += sW3[j] * (acc2 > 0.f ? acc2 : 0.2f * acc2);
    }
    red[t] = partial;
    __syncthreads();
    if (q == 0) out[n] = red[t] + red[t + 1] + red[t + 2] + red[t + 3];
}

extern "C" void kernel_launch(void* const* d_in, const int* in_sizes, int n_in,
                              void* d_out, int out_size, void* d_ws, size_t ws_size,
                              hipStream_t stream) {
    (void)in_sizes; (void)n_in; (void)out_size; (void)ws_size;
    const int*   dots   = (const int*)d_in[0];
    const float* w_each = (const float*)d_in[1];
    const float* w_not  = (const float*)d_in[2];
    const float* w_not2 = (const float*)d_in[3];
    const float* w_emp  = (const float*)d_in[4];
    const float* W1 = (const float*)d_in[5];
    const float* W2 = (const float*)d_in[6];
    const float* W3 = (const float*)d_in[7];
    float* out = (float*)d_out;

    char* ws = (char*)d_ws;
    size_t off = 0;
    auto alloc = [&](size_t bytes) -> char* {
        char* p = ws + off;
        off += (bytes + 255) & ~(size_t)255;
        return p;
    };
    f16* Mn    = (f16*)alloc((size_t)PIX * PIX * 2);
    f16* Mn2   = (f16*)alloc((size_t)PIX * PIX * 2);
    f16* BstS1 = (f16*)alloc((size_t)PIX * PIX * 2);
    f16* BstE  = (f16*)alloc((size_t)2048 * PIX * 2);
    f16* W1b   = (f16*)alloc((size_t)128 * PIX * 2);
    unsigned char* board = (unsigned char*)alloc((size_t)NB * PIX);
    f16* Xe    = (f16*)alloc((size_t)MR * PIX * 2);
    f16* Xn    = (f16*)alloc((size_t)MR * PIX * 2);
    f16* Xz    = (f16*)alloc((size_t)NB * PIX * 2);
    f16* NC    = (f16*)alloc((size_t)MR * PIX * 2);
    f16* EnBoth= (f16*)alloc((size_t)2 * NB * PIX * 2);   // [En | Eplus-tn]
    f16* S1sel = (f16*)alloc((size_t)NB * PIX * 2);
    f16* Sa    = (f16*)alloc((size_t)NB * PIX * 2);
    f16* Sb    = (f16*)alloc((size_t)NB * PIX * 2);
    f16* feat  = (f16*)alloc((size_t)NB * PIX * 2);
    float* Lsel= (float*)alloc((size_t)NB * PIX * 4);
    float* tn  = (float*)alloc((size_t)PIX * 4);
    float* X1  = (float*)alloc((size_t)NB * 128 * 4);

    build_board<<<1024, 256, 0, stream>>>(dots, board);
    build_mats<<<4096, 256, 0, stream>>>(w_each, w_not, w_not2, w_emp,
                                         Mn, Mn2, BstS1, BstE);
    tn_build<<<4, 256, 0, stream>>>(Mn, tn);
    build_w1<<<512, 256, 0, stream>>>(W1, W1b);
    build_masks<<<16384, 256, 0, stream>>>(board, Xe, Xn, Xz);

    dim3 blk(256);
    // Phase A: stage1-raw + NC + En/Eplus, all pure-async, one dispatch
    gemm_fa<<<1280, blk, 0, stream>>>(Xe, Xn, Xz, BstS1, Mn, BstE, board, tn,
                                      S1sel, NC, EnBoth);
    f16* En = EnBoth;
    f16* EplusM = EnBoth + (size_t)NB * PIX;
    // Lsel / Sa
    mk_sa<<<16384, blk, 0, stream>>>(S1sel, EplusM, board, Lsel, Sa);
    // depth 1..3
    gemm_depth<3><<<512, blk, 0, stream>>>(Mn2, board, NC, Sa, En, Lsel, Sb);
    gemm_depth<3><<<512, blk, 0, stream>>>(Mn2, board, NC, Sb, En, Lsel, Sa);
    gemm_depth<3><<<512, blk, 0, stream>>>(Mn2, board, NC, Sa, En, Lsel, Sb);
    // depth 4 -> feat
    gemm_depth<4><<<512, blk, 0, stream>>>(Mn2, board, NC, Sb, En, Lsel, feat);
    // MLP
    gemm_mlp<<<32, blk, 0, stream>>>(feat, W1b, X1);
    mlp23<<<64, blk, 0, stream>>>(X1, W2, W3, out);
}

// Round 7
// 428.211 us; speedup vs baseline: 1.7633x; 1.7633x over previous
//
#include <hip/hip_runtime.h>
#include <cstdint>
#include <cstddef>

// ---------------------------------------------------------------------------
// NN_each_LN_exp: 33x33 SAME convs on 32x32 maps = dense 1024x1024 linear
// operators -> f16 MFMA GEMMs with fused epilogues. Row layout r = n*4+k:
// the 16x16x32 MFMA acc quad holds all 4 colors of one (n,o) cell.
// R7: measured-best shapes only. Depth = R2 kernel (sync NC*s staging, 32KB,
// acc[4][4]; 59us measured) + launch_bounds(256,4). Phase A = R5 fused
// pattern (824 TF measured) with reduced work: stage1 B=Me writes selected
// color only; -NC_sel folded into mk_sa as a gather from NC.
// ---------------------------------------------------------------------------

typedef _Float16 f16;
typedef __attribute__((ext_vector_type(8))) _Float16 f16x8;
typedef __attribute__((ext_vector_type(4))) float f32x4;

#define NB   4096
#define PIX  1024
#define MR   (NB * 4)

__device__ __forceinline__ void gld_lds16(const void* g, void* l) {
    __builtin_amdgcn_global_load_lds(
        (const __attribute__((address_space(1))) void*)g,
        (__attribute__((address_space(3))) void*)l, 16, 0, 0);
}

// Conv matrices (1024x1024 f16): M[o][in] = w[a-i+16][b-j+16]
__global__ void build_mats(const float* __restrict__ we, const float* __restrict__ wn,
                           const float* __restrict__ wn2, const float* __restrict__ wem,
                           f16* __restrict__ Me, f16* __restrict__ Mn,
                           f16* __restrict__ Mn2, f16* __restrict__ Mem) {
    int idx = blockIdx.x * 256 + threadIdx.x;
    int o = idx >> 10, in = idx & 1023;
    int i = o >> 5, j = o & 31, a = in >> 5, b = in & 31;
    int u = a - i + 16, v = b - j + 16;
    bool ok = (u >= 0) && (u < 33) && (v >= 0) && (v < 33);
    int w = u * 33 + v;
    float ve = 0.f, vn = 0.f, vn2 = 0.f, vem = 0.f;
    if (ok) { ve = we[w]; vn = wn[w]; vn2 = wn2[w]; vem = wem[w]; }
    Me[idx]  = (f16)ve;
    Mn[idx]  = (f16)vn;
    Mn2[idx] = (f16)vn2;
    Mem[idx] = (f16)vem;
}

// W1 (100,1024) fp32 -> padded (128,1024) f16
__global__ void build_w1(const float* __restrict__ W1, f16* __restrict__ W1b) {
    int idx = blockIdx.x * 256 + threadIdx.x;
    int j = idx >> 10, i = idx & 1023;
    W1b[idx] = (f16)(j < 100 ? W1[j * 1024 + i] : 0.f);
}

// dots (34,32,4096) int32, (v,h,b) -> board[n*1024+p] bytes, LDS transpose
__global__ void build_board(const int* __restrict__ dots, unsigned char* __restrict__ board) {
    __shared__ unsigned char tile[64][68];
    int t = threadIdx.x;
    int bp = blockIdx.x & 15, bn = blockIdx.x >> 4;
    int p0 = bp * 64, n0 = bn * 64;
    int ln = t & 63, lp = t >> 6;
#pragma unroll
    for (int j = 0; j < 16; j++) {
        int p = lp * 16 + j;
        tile[p][ln] = (unsigned char)dots[(size_t)(p0 + p) * 4096 + n0 + ln];
    }
    __syncthreads();
#pragma unroll
    for (int j = 0; j < 16; j++) {
        int n = lp * 16 + j;
        board[(size_t)(n0 + n) * 1024 + p0 + ln] = tile[ln][n];
    }
}

// L0 = S1sel + En - NC_sel (gather); Sa = sigmoid(L0)
__global__ void mk_sa(const f16* __restrict__ S1sel, const f16* __restrict__ En,
                      const f16* __restrict__ NC,
                      const unsigned char* __restrict__ board,
                      float* __restrict__ Lsel, f16* __restrict__ Sa) {
    int idx = blockIdx.x * 256 + threadIdx.x;      // n*1024+o
    int n = idx >> 10, o = idx & 1023;
    int c = board[idx];
    float L = 0.f;
    if (c > 0) {
        float ncsel = (float)NC[(size_t)(4 * n + c - 1) * 1024 + o];
        L = (float)S1sel[idx] + (float)En[idx] - ncsel;
    }
    Lsel[idx] = L;
    Sa[idx] = (f16)(1.f / (1.f + __expf(-L)));
}

// ---------------------------------------------------------------------------
// Core GEMM: C(M x N) = A(M x 1024) * B(N x 1024)^T, f16 in, f32 acc.
// BM=BN=128, BK=64, 4 waves as 2x2 (wave tile 64x64), 16x16x32 MFMA,
// XOR-swizzled chunks (R2-verified conflict-free).
// ASRC: 0 direct async   1 NC*s sync-staged (R2 pattern)
//       2 each(board)    3 notm(board)    4 empty(board)   [frag-time expand]
// MODE: 0 f16-out ldo    1 S1sel-select   3 depth   4 depth-final   5 f32 leaky
// ---------------------------------------------------------------------------
template <int MODE, int ASRC>
__device__ __forceinline__ void run_gemm(
    int bjob, int ypx, int nx, char* smem,
    const f16* __restrict__ X, const f16* __restrict__ B,
    const unsigned char* __restrict__ board, const f16* __restrict__ NCs,
    const f16* __restrict__ Sin, const f16* __restrict__ En,
    float* __restrict__ Lsel, f16* __restrict__ outB, int ldo,
    float* __restrict__ outF) {
    char* smB = smem;                              // 16 KB
    char* smA = smem + 16384;                      // f16 rows or board bytes

    const int tid = threadIdx.x;
    const int wv = tid >> 6, ln = tid & 63;
    const int wm = wv >> 1, wn_ = wv & 1;
    const int lr = ln & 15, lq = ln >> 4;

    int xcd = bjob & 7, slot = bjob >> 3;
    int bx = slot % nx;
    int by = xcd * ypx + slot / nx;
    const int rtile = by * 128, otile = bx * 128;
    const int img0 = (ASRC == 4) ? rtile : (rtile >> 2);

    const f32x4 fz = {0.f, 0.f, 0.f, 0.f};
    f32x4 acc[4][4];
#pragma unroll
    for (int i = 0; i < 4; i++)
#pragma unroll
        for (int j = 0; j < 4; j++) acc[i][j] = fz;

    for (int kb = 0; kb < 1024; kb += 64) {
        // ---- staging ----
#pragma unroll
        for (int t = 0; t < 4; t++) {              // B: async, 1024 chunks
            int c = (wv * 4 + t) * 64 + ln;
            int row = c >> 3, gcol = (c & 7) ^ (row & 7);
            gld_lds16(B + (size_t)(otile + row) * 1024 + kb + gcol * 8, smB + c * 16);
        }
        if (ASRC == 0) {
#pragma unroll
            for (int t = 0; t < 4; t++) {
                int c = (wv * 4 + t) * 64 + ln;
                int row = c >> 3, gcol = (c & 7) ^ (row & 7);
                gld_lds16(X + (size_t)(rtile + row) * 1024 + kb + gcol * 8, smA + c * 16);
            }
        } else if (ASRC == 1) {                    // NC*s product, sync (R2)
#pragma unroll
            for (int t = 0; t < 4; t++) {
                int c = (wv * 4 + t) * 64 + ln;
                int row = c >> 3, gcol = (c & 7) ^ (row & 7);
                int gr = rtile + row;
                f16x8 nc = *(const f16x8*)(NCs + (size_t)gr * 1024 + kb + gcol * 8);
                f16x8 sv = *(const f16x8*)(Sin + (size_t)(gr >> 2) * 1024 + kb + gcol * 8);
                *(f16x8*)(smA + c * 16) = nc * sv;
            }
        } else if (ASRC == 4) {                    // board: 128 maps = 512 slots
#pragma unroll
            for (int t = 0; t < 2; t++) {
                int c = t * 256 + wv * 64 + ln;
                int row = c >> 2, g = (c & 3) ^ (row & 3);
                gld_lds16(board + (size_t)(img0 + row) * 1024 + kb + g * 16, smA + c * 16);
            }
        } else {                                   // ASRC 2/3: 32 maps = 128 slots
            if (wv < 2) {
                int c = wv * 64 + ln;
                int row = c >> 2, g = (c & 3) ^ (row & 3);
                gld_lds16(board + (size_t)(img0 + row) * 1024 + kb + g * 16, smA + c * 16);
            }
        }
        __syncthreads();

        // ---- compute: 2 kk, oct = kk*4+lq in 0..7 ----
#pragma unroll
        for (int kk = 0; kk < 2; kk++) {
            const int oct = kk * 4 + lq;
            f16x8 af[4], bfr[4];
#pragma unroll
            for (int i = 0; i < 4; i++) {
                int rrow = wm * 64 + i * 16 + lr;
                if (ASRC == 0 || ASRC == 1) {
                    af[i] = *(const f16x8*)(smA + rrow * 128 + (oct ^ (rrow & 7)) * 16);
                } else {
                    int m = (ASRC == 4) ? rrow : (rrow >> 2);
                    int k1 = (rrow & 3) + 1;
                    uint64_t bb = *(const uint64_t*)(smA + m * 64 +
                                    ((oct >> 1) ^ (m & 3)) * 16 + (oct & 1) * 8);
                    f16x8 v;
#pragma unroll
                    for (int jj = 0; jj < 8; jj++) {
                        int bj = (int)((bb >> (8 * jj)) & 0xff);
                        bool on = (ASRC == 2) ? (bj == k1)
                                : (ASRC == 3) ? (bj != 0 && bj != k1)
                                              : (bj == 0);
                        v[jj] = on ? (f16)1.f : (f16)0.f;
                    }
                    af[i] = v;
                }
            }
#pragma unroll
            for (int j = 0; j < 4; j++) {
                int brow = wn_ * 64 + j * 16 + lr;
                bfr[j] = *(const f16x8*)(smB + brow * 128 + (oct ^ (brow & 7)) * 16);
            }
#pragma unroll
            for (int i = 0; i < 4; i++)
#pragma unroll
                for (int j = 0; j < 4; j++)
                    acc[i][j] = __builtin_amdgcn_mfma_f32_16x16x32_f16(
                        af[i], bfr[j], acc[i][j], 0, 0, 0);
        }
        __syncthreads();
    }

    // ---- epilogue ----
#pragma unroll
    for (int i = 0; i < 4; i++) {
        int rbase = rtile + wm * 64 + i * 16 + lq * 4;
#pragma unroll
        for (int j = 0; j < 4; j++) {
            int o = otile + wn_ * 64 + j * 16 + lr;
            f32x4 a = acc[i][j];
            if (MODE == 0) {
#pragma unroll
                for (int v = 0; v < 4; v++)
                    outB[(size_t)(rbase + v) * ldo + o] = (f16)a[v];
            } else if (MODE == 5) {
#pragma unroll
                for (int v = 0; v < 4; v++) {
                    float x = a[v];
                    outF[(size_t)(rbase + v) * ldo + o] = x > 0.f ? x : 0.2f * x;
                }
            } else {                               // 1,3,4: quad = 4 colors, cell n
                int n = rbase >> 2;
                size_t no = (size_t)n * PIX + o;
                int c = board[no];
                float asel = (c == 1) ? a[0] : (c == 2) ? a[1] : (c == 3) ? a[2] : a[3];
                if (MODE == 1) {
                    outB[no] = (f16)asel;          // selected conv_we(each)
                } else {
                    float E = (float)En[no];
                    float Lnew = (c > 0) ? (Lsel[no] + E + asel) : 0.f;
                    float s = 1.f / (1.f + __expf(-Lnew));
                    if (MODE != 4) Lsel[no] = Lnew;
                    outB[no] = (f16)s;
                }
            }
        }
    }
}

// Phase A: [0,1024) stage1-sel, [1024,2048) NC, [2048,2304) En
__global__ void __launch_bounds__(256, 4) gemm_fa(
    const f16* __restrict__ Me, const f16* __restrict__ Mn,
    const f16* __restrict__ Mem, const unsigned char* __restrict__ board,
    f16* __restrict__ S1sel, f16* __restrict__ NC, f16* __restrict__ En) {
    __shared__ __attribute__((aligned(16))) char smem[24576];
    int bi = blockIdx.x;
    if (bi < 1024) {
        run_gemm<1, 2>(bi, 16, 8, smem, nullptr, Me, board, nullptr, nullptr,
                       nullptr, nullptr, S1sel, 0, nullptr);
    } else if (bi < 2048) {
        run_gemm<0, 3>(bi - 1024, 16, 8, smem, nullptr, Mn, board, nullptr, nullptr,
                       nullptr, nullptr, NC, PIX, nullptr);
    } else {
        run_gemm<0, 4>(bi - 2048, 4, 8, smem, nullptr, Mem, board, nullptr, nullptr,
                       nullptr, nullptr, En, PIX, nullptr);
    }
}

// Depth GEMM: A = NC*s (sync-staged), MODE 3 (update L, write s) / 4 (feat)
template <int MODE>
__global__ void __launch_bounds__(256, 4) gemm_depth(
    const f16* __restrict__ Mn2, const unsigned char* __restrict__ board,
    const f16* __restrict__ NCs, const f16* __restrict__ Sin,
    const f16* __restrict__ En, float* __restrict__ Lsel,
    f16* __restrict__ outB) {
    __shared__ __attribute__((aligned(16))) char smem[32768];
    run_gemm<MODE, 1>(blockIdx.x, 16, 8, smem, nullptr, Mn2, board, NCs,
                      Sin, En, Lsel, outB, 0, nullptr);
}

// MLP layer 1: X1 = leaky(feat @ W1b^T), N=128
__global__ void __launch_bounds__(256, 4) gemm_mlp(
    const f16* __restrict__ feat, const f16* __restrict__ W1b,
    float* __restrict__ X1) {
    __shared__ __attribute__((aligned(16))) char smem[32768];
    run_gemm<5, 0>(blockIdx.x, 4, 1, smem, feat, W1b, nullptr, nullptr,
                   nullptr, nullptr, nullptr, nullptr, 128, X1);
}

// MLP layers 2+3
__global__ void __launch_bounds__(256) mlp23(const float* __restrict__ X1,
                                             const float* __restrict__ W2,
                                             const float* __restrict__ W3,
                                             float* __restrict__ out) {
    __shared__ float sW2[10000];
    __shared__ float sW3[100];
    __shared__ float red[256];
    int t = threadIdx.x;
    for (int idx = t; idx < 10000; idx += 256) sW2[idx] = W2[idx];
    if (t < 100) sW3[t] = W3[t];
    __syncthreads();
    int nb = t >> 2, q = t & 3;
    int n = blockIdx.x * 64 + nb;
    const float* x1 = X1 + (size_t)n * 128;
    float xr[100];
#pragma unroll
    for (int i = 0; i < 100; i++) xr[i] = x1[i];
    float partial = 0.f;
    for (int jj = 0; jj < 25; jj++) {
        int j = q + jj * 4;
        const float* w2r = sW2 + j * 100;
        float acc2 = 0.f;
#pragma unroll
        for (int i = 0; i < 100; i++) acc2 += w2r[i] * xr[i];
        partial += sW3[j] * (acc2 > 0.f ? acc2 : 0.2f * acc2);
    }
    red[t] = partial;
    __syncthreads();
    if (q == 0) out[n] = red[t] + red[t + 1] + red[t + 2] + red[t + 3];
}

extern "C" void kernel_launch(void* const* d_in, const int* in_sizes, int n_in,
                              void* d_out, int out_size, void* d_ws, size_t ws_size,
                              hipStream_t stream) {
    (void)in_sizes; (void)n_in; (void)out_size; (void)ws_size;
    const int*   dots   = (const int*)d_in[0];
    const float* w_each = (const float*)d_in[1];
    const float* w_not  = (const float*)d_in[2];
    const float* w_not2 = (const float*)d_in[3];
    const float* w_emp  = (const float*)d_in[4];
    const float* W1 = (const float*)d_in[5];
    const float* W2 = (const float*)d_in[6];
    const float* W3 = (const float*)d_in[7];
    float* out = (float*)d_out;

    char* ws = (char*)d_ws;
    size_t off = 0;
    auto alloc = [&](size_t bytes) -> char* {
        char* p = ws + off;
        off += (bytes + 255) & ~(size_t)255;
        return p;
    };
    f16* Me    = (f16*)alloc((size_t)PIX * PIX * 2);
    f16* Mn    = (f16*)alloc((size_t)PIX * PIX * 2);
    f16* Mn2   = (f16*)alloc((size_t)PIX * PIX * 2);
    f16* Mem   = (f16*)alloc((size_t)PIX * PIX * 2);
    f16* W1b   = (f16*)alloc((size_t)128 * PIX * 2);
    unsigned char* board = (unsigned char*)alloc((size_t)NB * PIX);
    f16* NC    = (f16*)alloc((size_t)MR * PIX * 2);
    f16* En    = (f16*)alloc((size_t)NB * PIX * 2);
    f16* S1sel = (f16*)alloc((size_t)NB * PIX * 2);
    f16* Sa    = (f16*)alloc((size_t)NB * PIX * 2);
    f16* Sb    = (f16*)alloc((size_t)NB * PIX * 2);
    f16* feat  = (f16*)alloc((size_t)NB * PIX * 2);
    float* Lsel= (float*)alloc((size_t)NB * PIX * 4);
    float* X1  = (float*)alloc((size_t)NB * 128 * 4);

    build_board<<<1024, 256, 0, stream>>>(dots, board);
    build_mats<<<4096, 256, 0, stream>>>(w_each, w_not, w_not2, w_emp,
                                         Me, Mn, Mn2, Mem);
    build_w1<<<512, 256, 0, stream>>>(W1, W1b);

    dim3 blk(256);
    // Phase A: stage1-sel + NC + En, one dispatch, 77.4 GF
    gemm_fa<<<2304, blk, 0, stream>>>(Me, Mn, Mem, board, S1sel, NC, En);
    // L0 / s0
    mk_sa<<<16384, blk, 0, stream>>>(S1sel, En, NC, board, Lsel, Sa);
    // depth 1..3
    gemm_depth<3><<<1024, blk, 0, stream>>>(Mn2, board, NC, Sa, En, Lsel, Sb);
    gemm_depth<3><<<1024, blk, 0, stream>>>(Mn2, board, NC, Sb, En, Lsel, Sa);
    gemm_depth<3><<<1024, blk, 0, stream>>>(Mn2, board, NC, Sa, En, Lsel, Sb);
    // depth 4 -> feat
    gemm_depth<4><<<1024, blk, 0, stream>>>(Mn2, board, NC, Sb, En, Lsel, feat);
    // MLP
    gemm_mlp<<<32, blk, 0, stream>>>(feat, W1b, X1);
    mlp23<<<64, blk, 0, stream>>>(X1, W2, W3, out);
}